// Round 14
// baseline (263.337 us; speedup 1.0000x reference)
//
#include <hip/hip_runtime.h>

#define HWn 3136
#define DIMc 1792
#define ZCc 1794
#define NBb 2
#define KP 1856      // K padded (58*32 = 29*64)
#define MP 3200      // i-dim padded per batch (25*128)

typedef unsigned short u16;
typedef unsigned int u32;
typedef unsigned char u8;
typedef short bf16x8 __attribute__((ext_vector_type(8)));
typedef float f32x4 __attribute__((ext_vector_type(4)));
typedef long lx2 __attribute__((ext_vector_type(2)));

#define GL_LDS(gp, lp) __builtin_amdgcn_global_load_lds(\
    (const __attribute__((address_space(1))) void*)(gp), \
    (__attribute__((address_space(3))) void*)(lp), 16, 0, 0)

__device__ __forceinline__ u16 f2b(float f) {
  u32 u = __float_as_uint(f);
  u32 r = (u + 0x7fffu + ((u >> 16) & 1u)) >> 16;
  return (u16)r;
}
__device__ __forceinline__ float b2f(u16 h) { return __uint_as_float((u32)h << 16); }

// pack 4 floats -> 4 OCP e4m3 bytes
__device__ __forceinline__ u32 pk4_fp8(float a, float b, float c, float d) {
  u32 lo = __builtin_amdgcn_cvt_pk_fp8_f32(a, b, 0, false);
  return __builtin_amdgcn_cvt_pk_fp8_f32(c, d, lo, true);
}
__device__ __forceinline__ u8 f2fp8(float v) {
  return (u8)(__builtin_amdgcn_cvt_pk_fp8_f32(v, v, 0, false) & 0xFF);
}

// bijective XCD-aware swizzle (m204)
__device__ __forceinline__ int xcd_swz(int orig, int nwg) {
  int q = nwg >> 3, r = nwg & 7;
  int xcd = orig & 7, j = orig >> 3;
  int base = (xcd < r) ? xcd * (q + 1) : r * (q + 1) + (xcd - r) * q;
  return base + j;
}

// ---------------- block reduce helpers (blockDim.x == 256) ----------------
__device__ __forceinline__ float blkSum256(float v) {
  __shared__ float sh[4];
  #pragma unroll
  for (int o = 32; o > 0; o >>= 1) v += __shfl_xor(v, o, 64);
  int lane = threadIdx.x & 63, w = threadIdx.x >> 6;
  if (lane == 0) sh[w] = v;
  __syncthreads();
  float r = sh[0] + sh[1] + sh[2] + sh[3];
  __syncthreads();
  return r;
}
__device__ __forceinline__ float blkMax256(float v) {
  __shared__ float sh[4];
  #pragma unroll
  for (int o = 32; o > 0; o >>= 1) v = fmaxf(v, __shfl_xor(v, o, 64));
  int lane = threadIdx.x & 63, w = threadIdx.x >> 6;
  if (lane == 0) sh[w] = v;
  __syncthreads();
  float r = fmaxf(fmaxf(sh[0], sh[1]), fmaxf(sh[2], sh[3]));
  __syncthreads();
  return r;
}
__device__ __forceinline__ float blkMin256(float v) {
  __shared__ float sh[4];
  #pragma unroll
  for (int o = 32; o > 0; o >>= 1) v = fminf(v, __shfl_xor(v, o, 64));
  int lane = threadIdx.x & 63, w = threadIdx.x >> 6;
  if (lane == 0) sh[w] = v;
  __syncthreads();
  float r = fminf(fminf(sh[0], sh[1]), fminf(sh[2], sh[3]));
  __syncthreads();
  return r;
}

// ---------------- 3x3 avg pool (count_include_pad -> /9), f32 ----------------
__global__ void pool_k(const float* __restrict__ in, float* __restrict__ out,
                       int total, int Hh, int Ww) {
  int idx = blockIdx.x * 256 + threadIdx.x;
  if (idx >= total) return;
  int w = idx % Ww; int h = (idx / Ww) % Hh; int bc = idx / (Ww * Hh);
  const float* p = in + (size_t)bc * Hh * Ww;
  float s = 0.f;
  #pragma unroll
  for (int dy = -1; dy <= 1; dy++) {
    int y = h + dy; if ((unsigned)y >= (unsigned)Hh) continue;
    #pragma unroll
    for (int dx = -1; dx <= 1; dx++) {
      int x = w + dx; if ((unsigned)x >= (unsigned)Ww) continue;
      s += p[y * Ww + x];
    }
  }
  out[idx] = s * (1.f / 9.f);
}

__device__ __forceinline__ float bilerp(const float* __restrict__ p, int Hin, int Win,
                                        int h, int w, float sc) {
  float fy = (h + 0.5f) * sc - 0.5f;
  float fx = (w + 0.5f) * sc - 0.5f;
  float y0f = floorf(fy), x0f = floorf(fx);
  int y0 = (int)y0f, x0 = (int)x0f;
  float wy = fy - y0f, wx = fx - x0f;
  int y0c = min(max(y0, 0), Hin - 1);
  int y1c = min(max(y0 + 1, 0), Hin - 1);
  int x0c = min(max(x0, 0), Win - 1);
  int x1c = min(max(x0 + 1, 0), Win - 1);
  float v00 = p[y0c * Win + x0c], v01 = p[y0c * Win + x1c];
  float v10 = p[y1c * Win + x0c], v11 = p[y1c * Win + x1c];
  return (1.f - wy) * ((1.f - wx) * v00 + wx * v01) + wy * ((1.f - wx) * v10 + wx * v11);
}

// ---------------- fused build+transpose: z_t8[b][i][c] fp8 interleaved + channel sums ----------------
// zt8 stored K-INTERLEAVED per 64-elem group (unit u -> ((u&3)<<1)|(u>>2)) for the fp8 BK=64 GEMM.
__global__ __launch_bounds__(256) void buildzt_k(const float* __restrict__ p1,
    const float* __restrict__ pp2, const float* __restrict__ pp3,
    u8* __restrict__ zt8, float* __restrict__ psum) {
  __shared__ u16 tile[64][68];
  int b = blockIdx.z;
  int i0 = blockIdx.x * 64;
  int c0 = blockIdx.y * 64;
  int t = threadIdx.x;
  #pragma unroll
  for (int q = 0; q < 16; q++) {
    int idx = q * 256 + t;
    int cp = idx >> 6, ip = idx & 63;
    int cg = c0 + cp;
    int ig = i0 + ip;
    int h = ig / 56, w = ig % 56;
    float val;
    if (cg < 256) {
      const float* p = p1 + (size_t)(b * 256 + cg) * HWn;
      float s = 0.f;
      #pragma unroll
      for (int dy = -1; dy <= 1; dy++) {
        int y = h + dy; if ((unsigned)y >= 56u) continue;
        #pragma unroll
        for (int dx = -1; dx <= 1; dx++) {
          int x = w + dx; if ((unsigned)x >= 56u) continue;
          s += p[y * 56 + x];
        }
      }
      val = s * (1.f / 9.f);
    } else if (cg < 768) {
      val = bilerp(pp2 + (size_t)(b * 512 + (cg - 256)) * 784, 28, 28, h, w, 0.5f);
    } else if (cg < 1792) {
      val = bilerp(pp3 + (size_t)(b * 1024 + (cg - 768)) * 196, 14, 14, h, w, 0.25f);
    } else if (cg == 1792) {
      val = -1.f + (2.f / 55.f) * (float)w;
    } else if (cg == 1793) {
      val = -1.f + (2.f / 55.f) * (float)h;
    } else {
      val = 0.f;
    }
    tile[cp][ip] = f2b(val);
  }
  __syncthreads();
  #pragma unroll
  for (int q = 0; q < 4; q++) {
    int idx = q * 256 + t;
    int r2 = idx >> 4;
    int cc4 = (idx & 15) * 4;
    u16 e0 = tile[cc4 + 0][r2], e1 = tile[cc4 + 1][r2];
    u16 e2 = tile[cc4 + 2][r2], e3 = tile[cc4 + 3][r2];
    u32 p8 = pk4_fp8(b2f(e0), b2f(e1), b2f(e2), b2f(e3));
    int u = cc4 >> 3, half4 = (cc4 >> 2) & 1;
    int up = ((u & 3) << 1) | (u >> 2);
    *reinterpret_cast<u32*>(&zt8[((size_t)b * MP + i0 + r2) * KP + c0 + up * 8 + half4 * 4]) = p8;
  }
  if (t < 64) {
    float s = 0.f;
    #pragma unroll 8
    for (int j = 0; j < 64; j++) s += b2f(tile[t][j]);
    psum[(((size_t)b * 29 + blockIdx.y) * 49 + blockIdx.x) * 64 + t] = s;
  }
}

// ---------------- reduce psum -> zmean[b][c] ----------------
__global__ void zred_k(const float* __restrict__ psum, float* __restrict__ zmean) {
  int cty = blockIdx.x, b = blockIdx.y;
  int t = threadIdx.x;  // 64 threads
  float s = 0.f;
  for (int ix = 0; ix < 49; ix++)
    s += psum[(((size_t)b * 29 + cty) * 49 + ix) * 64 + t];
  zmean[b * KP + cty * 64 + t] = s * (1.f / (float)HWn);
}

// ---------------- yv[b][o] = Wb[o,:] . zmean[b,:] + bias[o]  (bf16 Wb: eca gate accuracy) ----------------
__global__ __launch_bounds__(256) void yv_k(const u16* __restrict__ Wb, const float* __restrict__ zmean,
                                            const float* __restrict__ bias, float* __restrict__ yv) {
  __shared__ float zs[KP];
  int b = blockIdx.y;
  int o0 = blockIdx.x * 16;
  int t = threadIdx.x;
  for (int k = t; k < KP; k += 256) zs[k] = zmean[b * KP + k];
  __syncthreads();
  int w = t >> 6, l = t & 63;
  #pragma unroll
  for (int q = 0; q < 4; q++) {
    int o = o0 + w * 4 + q;
    const u16* R = Wb + (size_t)o * KP;
    float s = 0.f;
    for (int base = l * 8; base < KP; base += 512) {
      bf16x8 v = *reinterpret_cast<const bf16x8*>(&R[base]);
      #pragma unroll
      for (int j = 0; j < 8; j++) s += b2f((u16)v[j]) * zs[base + j];
    }
    #pragma unroll
    for (int off = 32; off > 0; off >>= 1) s += __shfl_xor(s, off, 64);
    if (l == 0) yv[b * DIMc + o] = s + bias[o];
  }
}

// ---------------- tiled transpose+convert: C -> C_t bf16 [3200][1856] + fp8 Ct8 (pad0) ----------------
// Ct8 rows stored K-INTERLEAVED per 64-elem group: 8B-unit u (=kk*4+c) at position (c<<1)|kk.
__global__ __launch_bounds__(256) void transC_k(const float* __restrict__ src, u16* __restrict__ dst,
                                                u8* __restrict__ dst8) {
  __shared__ u16 tile[64][68];
  int i0 = blockIdx.x * 64;
  int c0 = blockIdx.y * 64;
  int t = threadIdx.x;
  bool vi = (i0 < HWn);       // 3136 = 49*64: tile fully valid or fully pad
  #pragma unroll
  for (int q = 0; q < 4; q++) {
    int idx = q * 256 + t;
    int r = idx >> 4;
    int c4 = (idx & 15) * 4;
    int sr = c0 + r;
    if (vi && sr < DIMc) {
      float4 rv = *reinterpret_cast<const float4*>(&src[(size_t)sr * HWn + i0 + c4]);
      tile[r][c4 + 0] = f2b(rv.x); tile[r][c4 + 1] = f2b(rv.y);
      tile[r][c4 + 2] = f2b(rv.z); tile[r][c4 + 3] = f2b(rv.w);
    } else {
      tile[r][c4 + 0] = 0; tile[r][c4 + 1] = 0; tile[r][c4 + 2] = 0; tile[r][c4 + 3] = 0;
    }
  }
  __syncthreads();
  #pragma unroll
  for (int q = 0; q < 4; q++) {
    int idx = q * 256 + t;
    int r2 = idx >> 4;
    int cc4 = (idx & 15) * 4;
    u16 e0 = tile[cc4 + 0][r2], e1 = tile[cc4 + 1][r2];
    u16 e2 = tile[cc4 + 2][r2], e3 = tile[cc4 + 3][r2];
    u32 lo = (u32)e0 | ((u32)e1 << 16);
    u32 hi = (u32)e2 | ((u32)e3 << 16);
    *reinterpret_cast<uint2*>(&dst[(size_t)(i0 + r2) * KP + c0 + cc4]) = make_uint2(lo, hi);
    u32 p8 = pk4_fp8(b2f(e0), b2f(e1), b2f(e2), b2f(e3));
    int u = cc4 >> 3, half4 = (cc4 >> 2) & 1;          // 8B-unit in group, 4B half
    int up = ((u & 3) << 1) | (u >> 2);                // interleave: (c<<1)|kk
    *reinterpret_cast<u32*>(&dst8[(size_t)(i0 + r2) * KP + c0 + up * 8 + half4 * 4]) = p8;
  }
}

// ---------------- Wc f32 [1792][1794] -> bf16 Wb (for yv) + fp8 Wb8 interleaved (pad0) ----------------
__global__ void convW_k(const float* __restrict__ Wc, u16* __restrict__ Wb, u8* __restrict__ Wb8) {
  int idx = blockIdx.x * 256 + threadIdx.x;
  const int total = DIMc * KP;
  if (idx >= total) return;
  int k = idx % KP, m = idx / KP;
  float v = (k < ZCc) ? Wc[(size_t)m * ZCc + k] : 0.f;
  Wb[idx] = f2b(v);
  int g = k & ~63, u = (k >> 3) & 7, j = k & 7;
  int up = ((u & 3) << 1) | (u >> 2);
  Wb8[(size_t)m * KP + g + up * 8 + j] = f2fp8(v);
}

// ================= fp8 GEMM: 128x128 BK=64 dbuf (R12-proven bank geometry, 0 conflicts) =================
// A, B K-interleaved fp8. b128 frag reads, 16B-chunk swizzle (row>>1)&3 both-sides (rule #21).
// LDS 2 x (8KB+8KB) = 32KB -> 5 blocks/CU. Schedule: STAGE(t+1) -> ds_read -> MFMA -> 1 barrier.
// DIST==0: phi epilogue -> fp8 phi8 DIRECT (single rounding, interleaved bytes; no bf16 phi).
// DIST==1: dist epilogue (bf16 + min/max).
#define STAGE8(buf, koff) { _Pragma("unroll") for (int j = 0; j < 2; j++) { \
    GL_LDS(gA8[j] + (koff), &lA[buf][j * 4096 + tid * 16]); \
    GL_LDS(gB8[j] + (koff), &lB[buf][j * 4096 + tid * 16]); } }

template<int DIST>
__global__ __launch_bounds__(256, 5) void gemm8_k(
    const u8* __restrict__ A, const u8* __restrict__ B,
    int ntN, int NT,
    const float* __restrict__ bias, const float* __restrict__ fac,
    u8* __restrict__ Phi8Out,
    const float* __restrict__ feat2, const float* __restrict__ cent2,
    const float* __restrict__ kld, u16* __restrict__ DistB,
    float* __restrict__ mmpart, int nblk) {
  __shared__ u8 lA[2][128 * 64];
  __shared__ u8 lB[2][128 * 64];
  int tid = threadIdx.x;
  int wid = tid >> 6, lane = tid & 63;
  int wm = wid >> 1, wn = wid & 1;
  int orig = blockIdx.x;
  int wg = xcd_swz(orig, gridDim.x);
  int mt = wg / ntN, nt = wg % ntN;
  int m0 = mt * 128, n0 = nt * 128;
  // staging: thread -> row j*64 + (tid>>2), 16B chunk tid&3 (linear dest);
  // source chunk inverse-swizzled (rule #21): (tid&3) ^ ((row>>1)&3)
  int rbase = tid >> 2;                              // 0..63
  int csrc = (((tid & 3) ^ ((rbase >> 1) & 3)) << 4);
  const u8* gA8[2]; const u8* gB8[2];
  #pragma unroll
  for (int j = 0; j < 2; j++) {
    int rr = j * 64 + rbase;
    gA8[j] = A + (size_t)(m0 + rr) * KP + csrc;
    gB8[j] = B + (size_t)(n0 + rr) * KP + csrc;
  }
  // reader: lane (lr, c=lane>>4) b128 at chunk c ^ ((row>>1)&3); row>>1 swz = (lr>>1)&3
  int lr = lane & 15, c = lane >> 4;
  int chunkoff = ((c ^ ((lr >> 1) & 3)) << 4);
  int aoff = lr * 64 + chunkoff;
  f32x4 acc[4][4] = {};
  STAGE8(0, 0);
  __syncthreads();
  for (int t = 0; t < NT; t++) {
    int cur = t & 1;
    if (t + 1 < NT) STAGE8(cur ^ 1, (t + 1) * 64);
    lx2 av[4], bv[4];
    #pragma unroll
    for (int f = 0; f < 4; f++)
      av[f] = *reinterpret_cast<const lx2*>(&lA[cur][wm * 4096 + f * 1024 + aoff]);
    #pragma unroll
    for (int g = 0; g < 4; g++)
      bv[g] = *reinterpret_cast<const lx2*>(&lB[cur][wn * 4096 + g * 1024 + aoff]);
    #pragma unroll
    for (int f = 0; f < 4; f++)
      #pragma unroll
      for (int g = 0; g < 4; g++) {
        acc[f][g] = __builtin_amdgcn_mfma_f32_16x16x32_fp8_fp8(av[f][0], bv[g][0], acc[f][g], 0, 0, 0);
        acc[f][g] = __builtin_amdgcn_mfma_f32_16x16x32_fp8_fp8(av[f][1], bv[g][1], acc[f][g], 0, 0, 0);
      }
    __syncthreads();
  }
  int mbase = m0 + wm * 64 + (lane >> 4) * 4;
  int nbase = n0 + wn * 64 + lr;
  if (DIST == 0) {
    int bz0 = m0 / MP;   // tiles are batch-aligned (3200 = 25*128)
    float bvv[4], fcv[4];
    int pos8[4];
    #pragma unroll
    for (int ni = 0; ni < 4; ni++) {
      int n = nbase + ni * 16;
      bvv[ni] = bias[n];
      fcv[ni] = fac[bz0 * DIMc + n];
      int g = n & ~63, u = (n >> 3) & 7, j = n & 7;
      pos8[ni] = g + (((u & 3) << 1) | (u >> 2)) * 8 + j;   // interleaved byte position
    }
    #pragma unroll
    for (int mi = 0; mi < 4; mi++) {
      #pragma unroll
      for (int ni = 0; ni < 4; ni++) {
        #pragma unroll
        for (int r = 0; r < 4; r++) {
          int m = mbase + mi * 16 + r;
          Phi8Out[(size_t)m * KP + pos8[ni]] = f2fp8((acc[mi][ni][r] + bvv[ni]) * fcv[ni]);
        }
      }
    }
  } else {
    float lmin = 3.4e38f, lmax = -3.4e38f;
    #pragma unroll
    for (int mi = 0; mi < 4; mi++) {
      int m = mbase + mi * 16;
      int bz = m / MP;
      int i = m - bz * MP;
      float kl = kld[bz];
      float f2r[4];
      #pragma unroll
      for (int r = 0; r < 4; r++)
        f2r[r] = (i + r < HWn) ? feat2[bz * HWn + i + r] : 0.f;
      #pragma unroll
      for (int ni = 0; ni < 4; ni++) {
        int n = nbase + ni * 16;
        if (n < HWn) {
          float c2 = cent2[n];
          #pragma unroll
          for (int r = 0; r < 4; r++) {
            if (i + r < HWn) {
              float dd = (f2r[r] + c2 - 2.f * acc[mi][ni][r]) * kl;
              DistB[((size_t)bz * HWn + i + r) * HWn + n] = f2b(dd);
              lmin = fminf(lmin, dd); lmax = fmaxf(lmax, dd);
            }
          }
        }
      }
    }
    #pragma unroll
    for (int o = 32; o > 0; o >>= 1) {
      lmin = fminf(lmin, __shfl_xor(lmin, o, 64));
      lmax = fmaxf(lmax, __shfl_xor(lmax, o, 64));
    }
    __syncthreads();
    float* scr = reinterpret_cast<float*>(&lA[0][0]);
    if (lane == 0) { scr[wid] = lmin; scr[4 + wid] = lmax; }
    __syncthreads();
    if (tid == 0) {
      mmpart[orig] = fminf(fminf(scr[0], scr[1]), fminf(scr[2], scr[3]));
      mmpart[nblk + orig] = fmaxf(fmaxf(scr[4], scr[5]), fmaxf(scr[6], scr[7]));
    }
  }
}

// ---------------- eca conv1d k=9 + sigmoid -> scale factor ----------------
__global__ void fac_k(const float* __restrict__ yv, const float* __restrict__ weca,
                      float* __restrict__ fac) {
  int idx = blockIdx.x * 256 + threadIdx.x;
  if (idx >= NBb * DIMc) return;
  int o = idx % DIMc; int b = idx / DIMc;
  float s = 0.f;
  #pragma unroll
  for (int k = 0; k < 9; k++) {
    int c = o + k - 4;
    if ((unsigned)c < (unsigned)DIMc) s += yv[b * DIMc + c] * weca[k];
  }
  fac[idx] = 1.f + 0.1f / (1.f + expf(-s));
}

// ---------------- fused per-pixel row pass: cent2 + C softmax + feat2/kpart from phi8 ----------------
// phi8 read directly (HW dequant); K-interleaved unit tn = (t&~7)|((t&3)<<1)|((t>>2)&1).
// No phi writes; pad handling unnecessary (dist GEMM reads K<1792 only; m-pad rows guarded out).
__global__ __launch_bounds__(256) void rowfuse_k(const u16* __restrict__ Ct,
    const u8* __restrict__ Phi8, float* __restrict__ cent2,
    float* __restrict__ feat2, float* __restrict__ kpart) {
  int i = blockIdx.x;
  int t = threadIdx.x;
  int tn = (t & ~7) | ((t & 3) << 1) | ((t >> 2) & 1);   // interleaved 8B-unit position
  bool act = (t * 8 < DIMc);   // t < 224
  const u16* R = Ct + (size_t)i * KP;
  float c[8];
  float mc = -3.4e38f, c2 = 0.f;
  if (act) {
    bf16x8 x = *reinterpret_cast<const bf16x8*>(&R[t * 8]);
    #pragma unroll
    for (int j = 0; j < 8; j++) {
      c[j] = b2f((u16)x[j]);
      mc = fmaxf(mc, c[j]);
      c2 += c[j] * c[j];
    }
  }
  mc = blkMax256(mc);
  float se = 0.f, sce = 0.f;
  float e[8];
  if (act) {
    #pragma unroll
    for (int j = 0; j < 8; j++) {
      e[j] = expf(c[j] - mc);
      se += e[j]; sce += e[j] * (c[j] - mc);
    }
  }
  se = blkSum256(se);
  sce = blkSum256(sce);
  c2 = blkSum256(c2);
  if (t == 0) cent2[i] = c2;
  float tl = sce / se - logf(se);
  float inv_se = 1.f / se;
  #pragma unroll
  for (int b = 0; b < NBb; b++) {
    const u8* P8 = Phi8 + ((size_t)b * MP + i) * KP;
    float v[8];
    float mx = -3.4e38f;
    if (act) {
      uint2 x8 = *reinterpret_cast<const uint2*>(&P8[tn * 8]);
      v[0] = __builtin_amdgcn_cvt_f32_fp8((int)x8.x, 0);
      v[1] = __builtin_amdgcn_cvt_f32_fp8((int)x8.x, 1);
      v[2] = __builtin_amdgcn_cvt_f32_fp8((int)x8.x, 2);
      v[3] = __builtin_amdgcn_cvt_f32_fp8((int)x8.x, 3);
      v[4] = __builtin_amdgcn_cvt_f32_fp8((int)x8.y, 0);
      v[5] = __builtin_amdgcn_cvt_f32_fp8((int)x8.y, 1);
      v[6] = __builtin_amdgcn_cvt_f32_fp8((int)x8.y, 2);
      v[7] = __builtin_amdgcn_cvt_f32_fp8((int)x8.y, 3);
      #pragma unroll
      for (int j = 0; j < 8; j++) mx = fmaxf(mx, v[j]);
    }
    mx = blkMax256(mx);
    float sp = 0.f, f2 = 0.f, td = 0.f;
    if (act) {
      #pragma unroll
      for (int j = 0; j < 8; j++) {
        sp += expf(v[j] - mx);
        f2 += v[j] * v[j];
        td += e[j] * v[j];
      }
    }
    sp = blkSum256(sp);
    f2 = blkSum256(f2);
    td = blkSum256(td);
    if (t == 0) {
      feat2[b * HWn + i] = f2;
      kpart[b * HWn + i] = tl - td * inv_se + (mx + logf(sp));
    }
  }
}

__global__ __launch_bounds__(256) void kldred_k(const float* __restrict__ kpart, float* __restrict__ kld) {
  float s0 = 0.f, s1 = 0.f;
  for (int i = threadIdx.x; i < HWn; i += 256) { s0 += kpart[i]; s1 += kpart[HWn + i]; }
  s0 = blkSum256(s0); s1 = blkSum256(s1);
  if (threadIdx.x == 0) { kld[0] = s0; kld[1] = s1; }
}

// ---------------- global min/max reduce ----------------
__global__ __launch_bounds__(256) void mmred_k(const float* __restrict__ mmpart, float* __restrict__ gmm,
                                               int nblk) {
  float lmin = 3.4e38f, lmax = -3.4e38f;
  for (int i = threadIdx.x; i < nblk; i += 256) {
    lmin = fminf(lmin, mmpart[i]);
    lmax = fmaxf(lmax, mmpart[nblk + i]);
  }
  lmin = blkMin256(lmin); lmax = blkMax256(lmax);
  if (threadIdx.x == 0) { gmm[0] = lmin; gmm[1] = lmax; }
}

// ---------------- soft top-k: reference fixed-point, wave-per-row, rS in registers ----------------
__global__ __launch_bounds__(256) void topk_k(const u16* __restrict__ dist,
    const float* __restrict__ gmm, float* __restrict__ out) {
  int lane = threadIdx.x & 63;
  int row = blockIdx.x * 4 + (threadIdx.x >> 6);   // 4 independent waves per block
  const u16* dr = dist + (size_t)row * HWn;
  float gmin = gmm[0], gmax = gmm[1];
  float cmax = fmaxf(fmaxf(gmin * gmin, (gmin - 1.f) * (gmin - 1.f)),
                     fmaxf(gmax * gmax, (gmax - 1.f) * (gmax - 1.f)));
  float inv = 1.f / (0.1f * cmax);
  float rS[49];
  #pragma unroll
  for (int k = 0; k < 49; k++) {
    float dv = b2f(dr[k * 64 + lane]);
    rS[k] = expf((2.f * dv - 1.f) * inv);
  }
  const float nf = (float)HWn;
  float s = 1.f;
  for (int it = 0; it < 199; it++) {
    float loc = 0.f;
    #pragma unroll
    for (int k = 0; k < 49; k++)
      loc += __builtin_amdgcn_rcpf(fmaf(rS[k], s, 1.f));
    #pragma unroll
    for (int o = 32; o > 0; o >>= 1) loc += __shfl_xor(loc, o, 64);
    float snew = ((nf - 3.f) / 3.f) * loc * s / fmaxf(nf - loc, 1e-20f);
    float ds = fabsf(snew - s);
    s = snew;
    if (ds <= 1e-6f * fabsf(s)) break;
  }
  // final exact passes: A with true division; d recovered from log(rS)
  float A = 0.f, dl = 0.f;
  float hinv = 0.5f / inv;
  #pragma unroll
  for (int k = 0; k < 49; k++) {
    float w = 1.f / (1.f + rS[k] * s);
    A += w;
    float dv = fmaf(logf(rS[k]), hinv, 0.5f);    // d = 0.5*(log r / inv + 1)
    dl += dv * w;
  }
  #pragma unroll
  for (int o = 32; o > 0; o >>= 1) { A += __shfl_xor(A, o, 64); dl += __shfl_xor(dl, o, 64); }
  float dsum = dl * (3.f / A);
  if (lane == 0) out[row] = sqrtf(fmaxf(dsum, 0.f));
}

// ---------------- launch ----------------
extern "C" void kernel_launch(void* const* d_in, const int* in_sizes, int n_in,
                              void* d_out, int out_size, void* d_ws, size_t ws_size,
                              hipStream_t stream) {
  const float* p1 = (const float*)d_in[0];
  const float* p2 = (const float*)d_in[1];
  const float* p3 = (const float*)d_in[2];
  const float* wcoord = (const float*)d_in[3];
  const float* bcoord = (const float*)d_in[4];
  const float* weca = (const float*)d_in[5];
  const float* Cm = (const float*)d_in[6];
  float* out = (float*)d_out;
  float* ws = (float*)d_ws;

  // workspace layout (float units)
  // [0, 9834496) = dist bf16; overlays zt8/pp2/pp3 (dead before dist GEMM).
  // [9834496, 15120384) = phi8 + Ct8 + Wb8 (inside the old f32-dist reservation).
  u8*    zt8   = (u8*)ws;                           // fp8 2*3200*1856  -> 2,969,600 fl
  float* pp2   = ws + 5939200;                      // 802,816
  float* pp3   = ws + 6742016;                      // 401,408 (ends 7,143,424)
  u16*   dist  = (u16*)ws;                          // bf16 2*3136*3136 -> 9,834,496 fl
  u8*    phi8  = (u8*)(ws + 9834496);               // fp8 2*3200*1856  -> 2,969,600 fl
  u8*    Ct8   = (u8*)(ws + 12804096);              // fp8 3200*1856    -> 1,484,800 fl
  u8*    Wb8   = (u8*)(ws + 14288896);              // fp8 1792*1856    -> 831,488 fl (ends 15,120,384)
  u16*   Ct    = (u16*)(ws + 25608192);             // bf16 3200*1856   -> 2,969,600 fl
  u16*   Wb    = (u16*)(ws + 28577792);             // bf16 1792*1856   -> 1,662,976 fl
  float* yv    = ws + 30240768;                     // 3584
  float* fac   = yv + 3584;                         // 3584
  float* feat2 = fac + 3584;                        // 6272
  float* cent2 = feat2 + 6272;                      // 3136
  float* kpart = cent2 + 3136;                      // 6272
  float* kld   = kpart + 6272;                      // 2
  float* mmpart= kld + 2;                           // 2*1250
  float* gmm   = mmpart + 2500;                     // 2
  float* zmean = gmm + 2;                           // 2*1856 = 3712
  float* psum  = zmean + 3712;                      // 2*29*49*64 = 181,888
  const int NBLK = 50 * 25;                         // 1250 dist blocks

  // 1. pool p2, p3
  pool_k<<<3136, 256, 0, stream>>>(p2, pp2, NBb * 512 * 784, 28, 28);
  pool_k<<<1568, 256, 0, stream>>>(p3, pp3, NBb * 1024 * 196, 14, 14);
  // 2. fused build + transpose (fp8 interleaved) + channel partial sums
  buildzt_k<<<dim3(49, 29, NBb), 256, 0, stream>>>(p1, pp2, pp3, zt8, psum);
  zred_k<<<dim3(29, NBb), 64, 0, stream>>>(psum, zmean);
  // 3. weight convert (bf16 for eca + interleaved fp8 for GEMM) + C transpose
  convW_k<<<(DIMc * KP + 255) / 256, 256, 0, stream>>>(wcoord, Wb, Wb8);
  transC_k<<<dim3(50, 29, 1), 256, 0, stream>>>(Cm, Ct, Ct8);
  // 4. eca gate from zmean matvec
  yv_k<<<dim3(DIMc / 16, NBb), 256, 0, stream>>>(Wb, zmean, bcoord, yv);
  fac_k<<<(NBb * DIMc + 255) / 256, 256, 0, stream>>>(yv, weca, fac);
  // 5. phi8 = fp8((z_t @ Wb^T + bias) * fac), DIRECT fp8 out; fp8 BK=64, K=29 tiles
  gemm8_k<0><<<50 * 14, 256, 0, stream>>>(
      zt8, Wb8, 14, 29, bcoord, fac, phi8,
      nullptr, nullptr, nullptr, nullptr, nullptr, 0);
  // 6. fused row pass: cent2 + C softmax + feat2/kpart from phi8 (HW dequant)
  rowfuse_k<<<HWn, 256, 0, stream>>>(Ct, phi8, cent2, feat2, kpart);
  kldred_k<<<1, 256, 0, stream>>>(kpart, kld);
  // 7. dist = (feat2 + cent2 - 2 phi8 Ct8) * kld; fp8 BK=64, K=28 tiles (pad channels unread)
  gemm8_k<1><<<50 * 25, 256, 0, stream>>>(
      phi8, Ct8, 25, 28, nullptr, nullptr, nullptr,
      feat2, cent2, kld, dist, mmpart, NBLK);
  mmred_k<<<1, 256, 0, stream>>>(mmpart, gmm, NBLK);
  // 8. soft top-k (wave-per-row fixed-point) + weighted sum + sqrt
  topk_k<<<NBb * HWn / 4, 256, 0, stream>>>(dist, gmm, out);
}

// Round 15
// 260.162 us; speedup vs baseline: 1.0122x; 1.0122x over previous
//
#include <hip/hip_runtime.h>

#define HWn 3136
#define DIMc 1792
#define ZCc 1794
#define NBb 2
#define KP 1856      // K padded (58*32 = 29*64)
#define MP 3200      // i-dim padded per batch (25*128)

typedef unsigned short u16;
typedef unsigned int u32;
typedef unsigned char u8;
typedef short bf16x8 __attribute__((ext_vector_type(8)));
typedef float f32x4 __attribute__((ext_vector_type(4)));
typedef long lx2 __attribute__((ext_vector_type(2)));

#define GL_LDS(gp, lp) __builtin_amdgcn_global_load_lds(\
    (const __attribute__((address_space(1))) void*)(gp), \
    (__attribute__((address_space(3))) void*)(lp), 16, 0, 0)

__device__ __forceinline__ u16 f2b(float f) {
  u32 u = __float_as_uint(f);
  u32 r = (u + 0x7fffu + ((u >> 16) & 1u)) >> 16;
  return (u16)r;
}
__device__ __forceinline__ float b2f(u16 h) { return __uint_as_float((u32)h << 16); }

// pack 4 floats -> 4 OCP e4m3 bytes
__device__ __forceinline__ u32 pk4_fp8(float a, float b, float c, float d) {
  u32 lo = __builtin_amdgcn_cvt_pk_fp8_f32(a, b, 0, false);
  return __builtin_amdgcn_cvt_pk_fp8_f32(c, d, lo, true);
}
__device__ __forceinline__ u8 f2fp8(float v) {
  return (u8)(__builtin_amdgcn_cvt_pk_fp8_f32(v, v, 0, false) & 0xFF);
}

// bijective XCD-aware swizzle (m204)
__device__ __forceinline__ int xcd_swz(int orig, int nwg) {
  int q = nwg >> 3, r = nwg & 7;
  int xcd = orig & 7, j = orig >> 3;
  int base = (xcd < r) ? xcd * (q + 1) : r * (q + 1) + (xcd - r) * q;
  return base + j;
}

// ---------------- block reduce helpers (blockDim.x == 256) ----------------
__device__ __forceinline__ float blkSum256(float v) {
  __shared__ float sh[4];
  #pragma unroll
  for (int o = 32; o > 0; o >>= 1) v += __shfl_xor(v, o, 64);
  int lane = threadIdx.x & 63, w = threadIdx.x >> 6;
  if (lane == 0) sh[w] = v;
  __syncthreads();
  float r = sh[0] + sh[1] + sh[2] + sh[3];
  __syncthreads();
  return r;
}
__device__ __forceinline__ float blkMax256(float v) {
  __shared__ float sh[4];
  #pragma unroll
  for (int o = 32; o > 0; o >>= 1) v = fmaxf(v, __shfl_xor(v, o, 64));
  int lane = threadIdx.x & 63, w = threadIdx.x >> 6;
  if (lane == 0) sh[w] = v;
  __syncthreads();
  float r = fmaxf(fmaxf(sh[0], sh[1]), fmaxf(sh[2], sh[3]));
  __syncthreads();
  return r;
}

// ---------------- fused 3x3 avg pool for p2 AND p3 (count_include_pad -> /9) ----------------
__global__ void poolf_k(const float* __restrict__ p2, float* __restrict__ pp2,
                        const float* __restrict__ p3, float* __restrict__ pp3) {
  int blk = blockIdx.x;
  const float* in; float* out; int total, Hh, Ww, idx;
  if (blk < 3136) { in = p2; out = pp2; total = NBb * 512 * 784; Hh = 28; Ww = 28; idx = blk * 256 + threadIdx.x; }
  else            { in = p3; out = pp3; total = NBb * 1024 * 196; Hh = 14; Ww = 14; idx = (blk - 3136) * 256 + threadIdx.x; }
  if (idx >= total) return;
  int w = idx % Ww; int h = (idx / Ww) % Hh; int bc = idx / (Ww * Hh);
  const float* p = in + (size_t)bc * Hh * Ww;
  float s = 0.f;
  #pragma unroll
  for (int dy = -1; dy <= 1; dy++) {
    int y = h + dy; if ((unsigned)y >= (unsigned)Hh) continue;
    #pragma unroll
    for (int dx = -1; dx <= 1; dx++) {
      int x = w + dx; if ((unsigned)x >= (unsigned)Ww) continue;
      s += p[y * Ww + x];
    }
  }
  out[idx] = s * (1.f / 9.f);
}

__device__ __forceinline__ float bilerp(const float* __restrict__ p, int Hin, int Win,
                                        int h, int w, float sc) {
  float fy = (h + 0.5f) * sc - 0.5f;
  float fx = (w + 0.5f) * sc - 0.5f;
  float y0f = floorf(fy), x0f = floorf(fx);
  int y0 = (int)y0f, x0 = (int)x0f;
  float wy = fy - y0f, wx = fx - x0f;
  int y0c = min(max(y0, 0), Hin - 1);
  int y1c = min(max(y0 + 1, 0), Hin - 1);
  int x0c = min(max(x0, 0), Win - 1);
  int x1c = min(max(x0 + 1, 0), Win - 1);
  float v00 = p[y0c * Win + x0c], v01 = p[y0c * Win + x1c];
  float v10 = p[y1c * Win + x0c], v11 = p[y1c * Win + x1c];
  return (1.f - wy) * ((1.f - wx) * v00 + wx * v01) + wy * ((1.f - wx) * v10 + wx * v11);
}

// ---------------- fused build+transpose: z_t8[b][i][c] fp8 interleaved + channel sums ----------------
// zt8 stored K-INTERLEAVED per 64-elem group (unit u -> ((u&3)<<1)|(u>>2)) for the fp8 BK=64 GEMM.
__global__ __launch_bounds__(256) void buildzt_k(const float* __restrict__ p1,
    const float* __restrict__ pp2, const float* __restrict__ pp3,
    u8* __restrict__ zt8, float* __restrict__ psum) {
  __shared__ u16 tile[64][68];
  int b = blockIdx.z;
  int i0 = blockIdx.x * 64;
  int c0 = blockIdx.y * 64;
  int t = threadIdx.x;
  #pragma unroll
  for (int q = 0; q < 16; q++) {
    int idx = q * 256 + t;
    int cp = idx >> 6, ip = idx & 63;
    int cg = c0 + cp;
    int ig = i0 + ip;
    int h = ig / 56, w = ig % 56;
    float val;
    if (cg < 256) {
      const float* p = p1 + (size_t)(b * 256 + cg) * HWn;
      float s = 0.f;
      #pragma unroll
      for (int dy = -1; dy <= 1; dy++) {
        int y = h + dy; if ((unsigned)y >= 56u) continue;
        #pragma unroll
        for (int dx = -1; dx <= 1; dx++) {
          int x = w + dx; if ((unsigned)x >= 56u) continue;
          s += p[y * 56 + x];
        }
      }
      val = s * (1.f / 9.f);
    } else if (cg < 768) {
      val = bilerp(pp2 + (size_t)(b * 512 + (cg - 256)) * 784, 28, 28, h, w, 0.5f);
    } else if (cg < 1792) {
      val = bilerp(pp3 + (size_t)(b * 1024 + (cg - 768)) * 196, 14, 14, h, w, 0.25f);
    } else if (cg == 1792) {
      val = -1.f + (2.f / 55.f) * (float)w;
    } else if (cg == 1793) {
      val = -1.f + (2.f / 55.f) * (float)h;
    } else {
      val = 0.f;
    }
    tile[cp][ip] = f2b(val);
  }
  __syncthreads();
  #pragma unroll
  for (int q = 0; q < 4; q++) {
    int idx = q * 256 + t;
    int r2 = idx >> 4;
    int cc4 = (idx & 15) * 4;
    u16 e0 = tile[cc4 + 0][r2], e1 = tile[cc4 + 1][r2];
    u16 e2 = tile[cc4 + 2][r2], e3 = tile[cc4 + 3][r2];
    u32 p8 = pk4_fp8(b2f(e0), b2f(e1), b2f(e2), b2f(e3));
    int u = cc4 >> 3, half4 = (cc4 >> 2) & 1;
    int up = ((u & 3) << 1) | (u >> 2);
    *reinterpret_cast<u32*>(&zt8[((size_t)b * MP + i0 + r2) * KP + c0 + up * 8 + half4 * 4]) = p8;
  }
  if (t < 64) {
    float s = 0.f;
    #pragma unroll 8
    for (int j = 0; j < 64; j++) s += b2f(tile[t][j]);
    psum[(((size_t)b * 29 + blockIdx.y) * 49 + blockIdx.x) * 64 + t] = s;
  }
}

// ---------------- reduce psum -> zmean[b][c] ----------------
__global__ void zred_k(const float* __restrict__ psum, float* __restrict__ zmean) {
  int cty = blockIdx.x, b = blockIdx.y;
  int t = threadIdx.x;  // 64 threads
  float s = 0.f;
  for (int ix = 0; ix < 49; ix++)
    s += psum[(((size_t)b * 29 + cty) * 49 + ix) * 64 + t];
  zmean[b * KP + cty * 64 + t] = s * (1.f / (float)HWn);
}

// ---------------- yv[b][o] = Wb[o,:] . zmean[b,:] + bias[o]  (bf16 Wb: eca gate accuracy) ----------------
__global__ __launch_bounds__(256) void yv_k(const u16* __restrict__ Wb, const float* __restrict__ zmean,
                                            const float* __restrict__ bias, float* __restrict__ yv) {
  __shared__ float zs[KP];
  int b = blockIdx.y;
  int o0 = blockIdx.x * 16;
  int t = threadIdx.x;
  for (int k = t; k < KP; k += 256) zs[k] = zmean[b * KP + k];
  __syncthreads();
  int w = t >> 6, l = t & 63;
  #pragma unroll
  for (int q = 0; q < 4; q++) {
    int o = o0 + w * 4 + q;
    const u16* R = Wb + (size_t)o * KP;
    float s = 0.f;
    for (int base = l * 8; base < KP; base += 512) {
      bf16x8 v = *reinterpret_cast<const bf16x8*>(&R[base]);
      #pragma unroll
      for (int j = 0; j < 8; j++) s += b2f((u16)v[j]) * zs[base + j];
    }
    #pragma unroll
    for (int off = 32; off > 0; off >>= 1) s += __shfl_xor(s, off, 64);
    if (l == 0) yv[b * DIMc + o] = s + bias[o];
  }
}

// ---------------- tiled transpose+convert: C -> C_t bf16 [3200][1856] + fp8 Ct8 (pad0) ----------------
// Ct8 rows stored K-INTERLEAVED per 64-elem group: 8B-unit u (=kk*4+c) at position (c<<1)|kk.
__global__ __launch_bounds__(256) void transC_k(const float* __restrict__ src, u16* __restrict__ dst,
                                                u8* __restrict__ dst8) {
  __shared__ u16 tile[64][68];
  int i0 = blockIdx.x * 64;
  int c0 = blockIdx.y * 64;
  int t = threadIdx.x;
  bool vi = (i0 < HWn);       // 3136 = 49*64: tile fully valid or fully pad
  #pragma unroll
  for (int q = 0; q < 4; q++) {
    int idx = q * 256 + t;
    int r = idx >> 4;
    int c4 = (idx & 15) * 4;
    int sr = c0 + r;
    if (vi && sr < DIMc) {
      float4 rv = *reinterpret_cast<const float4*>(&src[(size_t)sr * HWn + i0 + c4]);
      tile[r][c4 + 0] = f2b(rv.x); tile[r][c4 + 1] = f2b(rv.y);
      tile[r][c4 + 2] = f2b(rv.z); tile[r][c4 + 3] = f2b(rv.w);
    } else {
      tile[r][c4 + 0] = 0; tile[r][c4 + 1] = 0; tile[r][c4 + 2] = 0; tile[r][c4 + 3] = 0;
    }
  }
  __syncthreads();
  #pragma unroll
  for (int q = 0; q < 4; q++) {
    int idx = q * 256 + t;
    int r2 = idx >> 4;
    int cc4 = (idx & 15) * 4;
    u16 e0 = tile[cc4 + 0][r2], e1 = tile[cc4 + 1][r2];
    u16 e2 = tile[cc4 + 2][r2], e3 = tile[cc4 + 3][r2];
    u32 lo = (u32)e0 | ((u32)e1 << 16);
    u32 hi = (u32)e2 | ((u32)e3 << 16);
    *reinterpret_cast<uint2*>(&dst[(size_t)(i0 + r2) * KP + c0 + cc4]) = make_uint2(lo, hi);
    u32 p8 = pk4_fp8(b2f(e0), b2f(e1), b2f(e2), b2f(e3));
    int u = cc4 >> 3, half4 = (cc4 >> 2) & 1;          // 8B-unit in group, 4B half
    int up = ((u & 3) << 1) | (u >> 2);                // interleave: (c<<1)|kk
    *reinterpret_cast<u32*>(&dst8[(size_t)(i0 + r2) * KP + c0 + up * 8 + half4 * 4]) = p8;
  }
}

// ---------------- Wc f32 [1792][1794] -> bf16 Wb (for yv) + fp8 Wb8 interleaved (pad0) ----------------
__global__ void convW_k(const float* __restrict__ Wc, u16* __restrict__ Wb, u8* __restrict__ Wb8) {
  int idx = blockIdx.x * 256 + threadIdx.x;
  const int total = DIMc * KP;
  if (idx >= total) return;
  int k = idx % KP, m = idx / KP;
  float v = (k < ZCc) ? Wc[(size_t)m * ZCc + k] : 0.f;
  Wb[idx] = f2b(v);
  int g = k & ~63, u = (k >> 3) & 7, j = k & 7;
  int up = ((u & 3) << 1) | (u >> 2);
  Wb8[(size_t)m * KP + g + up * 8 + j] = f2fp8(v);
}

// ================= fp8 GEMM: 128x128 BK=64 dbuf (R12-proven bank geometry, 0 conflicts) =================
// A, B K-interleaved fp8. b128 frag reads, 16B-chunk swizzle (row>>1)&3 both-sides (rule #21).
// LDS 2 x (8KB+8KB) = 32KB -> 5 blocks/CU. Schedule: STAGE(t+1) -> ds_read -> MFMA -> 1 barrier.
// DIST==0: phi epilogue (bias + eca fac scale, bf16 out). DIST==1: dist epilogue (bf16 + min/max).
#define STAGE8(buf, koff) { _Pragma("unroll") for (int j = 0; j < 2; j++) { \
    GL_LDS(gA8[j] + (koff), &lA[buf][j * 4096 + tid * 16]); \
    GL_LDS(gB8[j] + (koff), &lB[buf][j * 4096 + tid * 16]); } }

template<int DIST>
__global__ __launch_bounds__(256, 5) void gemm8_k(
    const u8* __restrict__ A, const u8* __restrict__ B,
    int ntN, int NT,
    const float* __restrict__ bias, const float* __restrict__ fac,
    u16* __restrict__ PhiOut,
    const float* __restrict__ feat2, const float* __restrict__ cent2,
    const float* __restrict__ kld, u16* __restrict__ DistB,
    float* __restrict__ mmpart, int nblk) {
  __shared__ u8 lA[2][128 * 64];
  __shared__ u8 lB[2][128 * 64];
  int tid = threadIdx.x;
  int wid = tid >> 6, lane = tid & 63;
  int wm = wid >> 1, wn = wid & 1;
  int orig = blockIdx.x;
  int wg = xcd_swz(orig, gridDim.x);
  int mt = wg / ntN, nt = wg % ntN;
  int m0 = mt * 128, n0 = nt * 128;
  // staging: thread -> row j*64 + (tid>>2), 16B chunk tid&3 (linear dest);
  // source chunk inverse-swizzled (rule #21): (tid&3) ^ ((row>>1)&3)
  int rbase = tid >> 2;                              // 0..63
  int csrc = (((tid & 3) ^ ((rbase >> 1) & 3)) << 4);
  const u8* gA8[2]; const u8* gB8[2];
  #pragma unroll
  for (int j = 0; j < 2; j++) {
    int rr = j * 64 + rbase;
    gA8[j] = A + (size_t)(m0 + rr) * KP + csrc;
    gB8[j] = B + (size_t)(n0 + rr) * KP + csrc;
  }
  // reader: lane (lr, c=lane>>4) b128 at chunk c ^ ((row>>1)&3); row>>1 swz = (lr>>1)&3
  int lr = lane & 15, c = lane >> 4;
  int chunkoff = ((c ^ ((lr >> 1) & 3)) << 4);
  int aoff = lr * 64 + chunkoff;
  f32x4 acc[4][4] = {};
  STAGE8(0, 0);
  __syncthreads();
  for (int t = 0; t < NT; t++) {
    int cur = t & 1;
    if (t + 1 < NT) STAGE8(cur ^ 1, (t + 1) * 64);
    lx2 av[4], bv[4];
    #pragma unroll
    for (int f = 0; f < 4; f++)
      av[f] = *reinterpret_cast<const lx2*>(&lA[cur][wm * 4096 + f * 1024 + aoff]);
    #pragma unroll
    for (int g = 0; g < 4; g++)
      bv[g] = *reinterpret_cast<const lx2*>(&lB[cur][wn * 4096 + g * 1024 + aoff]);
    #pragma unroll
    for (int f = 0; f < 4; f++)
      #pragma unroll
      for (int g = 0; g < 4; g++) {
        acc[f][g] = __builtin_amdgcn_mfma_f32_16x16x32_fp8_fp8(av[f][0], bv[g][0], acc[f][g], 0, 0, 0);
        acc[f][g] = __builtin_amdgcn_mfma_f32_16x16x32_fp8_fp8(av[f][1], bv[g][1], acc[f][g], 0, 0, 0);
      }
    __syncthreads();
  }
  int mbase = m0 + wm * 64 + (lane >> 4) * 4;
  int nbase = n0 + wn * 64 + lr;
  if (DIST == 0) {
    int bz0 = m0 / MP;   // tiles are batch-aligned (3200 = 25*128)
    float bvv[4], fcv[4];
    #pragma unroll
    for (int ni = 0; ni < 4; ni++) {
      int n = nbase + ni * 16;
      bvv[ni] = bias[n];
      fcv[ni] = fac[bz0 * DIMc + n];
    }
    #pragma unroll
    for (int mi = 0; mi < 4; mi++) {
      #pragma unroll
      for (int ni = 0; ni < 4; ni++) {
        int n = nbase + ni * 16;
        #pragma unroll
        for (int r = 0; r < 4; r++) {
          int m = mbase + mi * 16 + r;
          PhiOut[(size_t)m * KP + n] = f2b((acc[mi][ni][r] + bvv[ni]) * fcv[ni]);
        }
      }
    }
  } else {
    float lmin = 3.4e38f, lmax = -3.4e38f;
    #pragma unroll
    for (int mi = 0; mi < 4; mi++) {
      int m = mbase + mi * 16;
      int bz = m / MP;
      int i = m - bz * MP;
      float kl = kld[bz];
      float f2r[4];
      #pragma unroll
      for (int r = 0; r < 4; r++)
        f2r[r] = (i + r < HWn) ? feat2[bz * HWn + i + r] : 0.f;
      #pragma unroll
      for (int ni = 0; ni < 4; ni++) {
        int n = nbase + ni * 16;
        if (n < HWn) {
          float c2 = cent2[n];
          #pragma unroll
          for (int r = 0; r < 4; r++) {
            if (i + r < HWn) {
              float dd = (f2r[r] + c2 - 2.f * acc[mi][ni][r]) * kl;
              DistB[((size_t)bz * HWn + i + r) * HWn + n] = f2b(dd);
              lmin = fminf(lmin, dd); lmax = fmaxf(lmax, dd);
            }
          }
        }
      }
    }
    #pragma unroll
    for (int o = 32; o > 0; o >>= 1) {
      lmin = fminf(lmin, __shfl_xor(lmin, o, 64));
      lmax = fmaxf(lmax, __shfl_xor(lmax, o, 64));
    }
    __syncthreads();
    float* scr = reinterpret_cast<float*>(&lA[0][0]);
    if (lane == 0) { scr[wid] = lmin; scr[4 + wid] = lmax; }
    __syncthreads();
    if (tid == 0) {
      mmpart[orig] = fminf(fminf(scr[0], scr[1]), fminf(scr[2], scr[3]));
      mmpart[nblk + orig] = fmaxf(fmaxf(scr[4], scr[5]), fmaxf(scr[6], scr[7]));
    }
  }
}

// ---------------- eca conv1d k=9 + sigmoid -> scale factor ----------------
__global__ void fac_k(const float* __restrict__ yv, const float* __restrict__ weca,
                      float* __restrict__ fac) {
  int idx = blockIdx.x * 256 + threadIdx.x;
  if (idx >= NBb * DIMc) return;
  int o = idx % DIMc; int b = idx / DIMc;
  float s = 0.f;
  #pragma unroll
  for (int k = 0; k < 9; k++) {
    int c = o + k - 4;
    if ((unsigned)c < (unsigned)DIMc) s += yv[b * DIMc + c] * weca[k];
  }
  fac[idx] = 1.f + 0.1f / (1.f + expf(-s));
}

// ---------------- fused per-pixel row pass: cent2 + C softmax + feat2/kpart + phi8 emit ----------------
// phi8 written K-INTERLEAVED (unit t -> (t&~7) | ((t&3)<<1) | ((t>>2)&1)) to match gemm8.
__global__ __launch_bounds__(256) void rowfuse_k(const u16* __restrict__ Ct, u16* __restrict__ Phi,
    u8* __restrict__ Phi8, float* __restrict__ cent2,
    float* __restrict__ feat2, float* __restrict__ kpart) {
  int i = blockIdx.x;
  int t = threadIdx.x;
  int tn = (t & ~7) | ((t & 3) << 1) | ((t >> 2) & 1);   // interleaved 8B-unit position
  if (i >= HWn) {              // pad rows: zero phi8 for both batches
    if (t * 8 < KP) {
      #pragma unroll
      for (int b = 0; b < NBb; b++)
        *reinterpret_cast<uint2*>(&Phi8[((size_t)b * MP + i) * KP + tn * 8]) = make_uint2(0, 0);
    }
    return;
  }
  bool act = (t * 8 < DIMc);   // t < 224
  const u16* R = Ct + (size_t)i * KP;
  float c[8];
  float mc = -3.4e38f, c2 = 0.f;
  if (act) {
    bf16x8 x = *reinterpret_cast<const bf16x8*>(&R[t * 8]);
    #pragma unroll
    for (int j = 0; j < 8; j++) {
      c[j] = b2f((u16)x[j]);
      mc = fmaxf(mc, c[j]);
      c2 += c[j] * c[j];
    }
  }
  mc = blkMax256(mc);
  float se = 0.f, sce = 0.f;
  float e[8];
  if (act) {
    #pragma unroll
    for (int j = 0; j < 8; j++) {
      e[j] = expf(c[j] - mc);
      se += e[j]; sce += e[j] * (c[j] - mc);
    }
  }
  se = blkSum256(se);
  sce = blkSum256(sce);
  c2 = blkSum256(c2);
  if (t == 0) cent2[i] = c2;
  float tl = sce / se - logf(se);
  float inv_se = 1.f / se;
  #pragma unroll
  for (int b = 0; b < NBb; b++) {
    u16* P = Phi + (size_t)b * MP * KP + (size_t)i * KP;
    u8* P8 = Phi8 + ((size_t)b * MP + i) * KP;
    float v[8];
    float mx = -3.4e38f;
    if (act) {
      bf16x8 x = *reinterpret_cast<const bf16x8*>(&P[t * 8]);
      #pragma unroll
      for (int j = 0; j < 8; j++) {
        v[j] = b2f((u16)x[j]);
        mx = fmaxf(mx, v[j]);
      }
      uint2 p8;
      p8.x = pk4_fp8(v[0], v[1], v[2], v[3]);
      p8.y = pk4_fp8(v[4], v[5], v[6], v[7]);
      *reinterpret_cast<uint2*>(&P8[tn * 8]) = p8;
    } else if (t * 8 < KP) {       // zero K-pad (once; phi GEMM writes n<1792 only)
      bf16x8 zr = {};
      *reinterpret_cast<bf16x8*>(&P[t * 8]) = zr;
      *reinterpret_cast<uint2*>(&P8[tn * 8]) = make_uint2(0, 0);
    }
    mx = blkMax256(mx);
    float sp = 0.f, f2 = 0.f, td = 0.f;
    if (act) {
      #pragma unroll
      for (int j = 0; j < 8; j++) {
        sp += expf(v[j] - mx);
        f2 += v[j] * v[j];
        td += e[j] * v[j];
      }
    }
    sp = blkSum256(sp);
    f2 = blkSum256(f2);
    td = blkSum256(td);
    if (t == 0) {
      feat2[b * HWn + i] = f2;
      kpart[b * HWn + i] = tl - td * inv_se + (mx + logf(sp));
    }
  }
}

__global__ __launch_bounds__(256) void kldred_k(const float* __restrict__ kpart, float* __restrict__ kld) {
  float s0 = 0.f, s1 = 0.f;
  for (int i = threadIdx.x; i < HWn; i += 256) { s0 += kpart[i]; s1 += kpart[HWn + i]; }
  s0 = blkSum256(s0); s1 = blkSum256(s1);
  if (threadIdx.x == 0) { kld[0] = s0; kld[1] = s1; }
}

// ---------------- soft top-k: fixed-point wave-per-row, rS in registers; mmred FOLDED IN ----------------
// Each wave reduces mmpart[0..nblk) min / [nblk..2nblk) max itself (L2-broadcast 10KB, ~40 loads
// + 12 shfl) -- removes the serial mmred_k launch from the critical path. No block syncs anywhere.
__global__ __launch_bounds__(256) void topk_k(const u16* __restrict__ dist,
    const float* __restrict__ mmpart, int nblk, float* __restrict__ out) {
  int lane = threadIdx.x & 63;
  int row = blockIdx.x * 4 + (threadIdx.x >> 6);   // 4 independent waves per block
  const u16* dr = dist + (size_t)row * HWn;
  float gmin = 3.4e38f, gmax = -3.4e38f;
  for (int i = lane; i < nblk; i += 64) {
    gmin = fminf(gmin, mmpart[i]);
    gmax = fmaxf(gmax, mmpart[nblk + i]);
  }
  #pragma unroll
  for (int o = 32; o > 0; o >>= 1) {
    gmin = fminf(gmin, __shfl_xor(gmin, o, 64));
    gmax = fmaxf(gmax, __shfl_xor(gmax, o, 64));
  }
  float cmax = fmaxf(fmaxf(gmin * gmin, (gmin - 1.f) * (gmin - 1.f)),
                     fmaxf(gmax * gmax, (gmax - 1.f) * (gmax - 1.f)));
  float inv = 1.f / (0.1f * cmax);
  float rS[49];
  #pragma unroll
  for (int k = 0; k < 49; k++) {
    float dv = b2f(dr[k * 64 + lane]);
    rS[k] = expf((2.f * dv - 1.f) * inv);
  }
  const float nf = (float)HWn;
  float s = 1.f;
  for (int it = 0; it < 199; it++) {
    float loc = 0.f;
    #pragma unroll
    for (int k = 0; k < 49; k++)
      loc += __builtin_amdgcn_rcpf(fmaf(rS[k], s, 1.f));
    #pragma unroll
    for (int o = 32; o > 0; o >>= 1) loc += __shfl_xor(loc, o, 64);
    float snew = ((nf - 3.f) / 3.f) * loc * s / fmaxf(nf - loc, 1e-20f);
    float ds = fabsf(snew - s);
    s = snew;
    if (ds <= 1e-6f * fabsf(s)) break;
  }
  // final exact passes: A with true division; d recovered from log(rS)
  float A = 0.f, dl = 0.f;
  float hinv = 0.5f / inv;
  #pragma unroll
  for (int k = 0; k < 49; k++) {
    float w = 1.f / (1.f + rS[k] * s);
    A += w;
    float dv = fmaf(logf(rS[k]), hinv, 0.5f);    // d = 0.5*(log r / inv + 1)
    dl += dv * w;
  }
  #pragma unroll
  for (int o = 32; o > 0; o >>= 1) { A += __shfl_xor(A, o, 64); dl += __shfl_xor(dl, o, 64); }
  float dsum = dl * (3.f / A);
  if (lane == 0) out[row] = sqrtf(fmaxf(dsum, 0.f));
}

// ---------------- launch ----------------
extern "C" void kernel_launch(void* const* d_in, const int* in_sizes, int n_in,
                              void* d_out, int out_size, void* d_ws, size_t ws_size,
                              hipStream_t stream) {
  const float* p1 = (const float*)d_in[0];
  const float* p2 = (const float*)d_in[1];
  const float* p3 = (const float*)d_in[2];
  const float* wcoord = (const float*)d_in[3];
  const float* bcoord = (const float*)d_in[4];
  const float* weca = (const float*)d_in[5];
  const float* Cm = (const float*)d_in[6];
  float* out = (float*)d_out;
  float* ws = (float*)d_ws;

  // workspace layout (float units)
  // [0, 9834496) = dist bf16; overlays zt8/pp2/pp3 (dead before dist GEMM).
  // [9834496, 15120384) = phi8 + Ct8 + Wb8 (inside the old f32-dist reservation).
  u8*    zt8   = (u8*)ws;                           // fp8 2*3200*1856  -> 2,969,600 fl
  float* pp2   = ws + 5939200;                      // 802,816
  float* pp3   = ws + 6742016;                      // 401,408 (ends 7,143,424)
  u16*   dist  = (u16*)ws;                          // bf16 2*3136*3136 -> 9,834,496 fl
  u8*    phi8  = (u8*)(ws + 9834496);               // fp8 2*3200*1856  -> 2,969,600 fl
  u8*    Ct8   = (u8*)(ws + 12804096);              // fp8 3200*1856    -> 1,484,800 fl
  u8*    Wb8   = (u8*)(ws + 14288896);              // fp8 1792*1856    -> 831,488 fl (ends 15,120,384)
  u16*   phi   = (u16*)(ws + 19668992);             // bf16 2*3200*1856 -> 5,939,200 fl
  u16*   Ct    = (u16*)(ws + 25608192);             // bf16 3200*1856   -> 2,969,600 fl
  u16*   Wb    = (u16*)(ws + 28577792);             // bf16 1792*1856   -> 1,662,976 fl
  float* yv    = ws + 30240768;                     // 3584
  float* fac   = yv + 3584;                         // 3584
  float* feat2 = fac + 3584;                        // 6272
  float* cent2 = feat2 + 6272;                      // 3136
  float* kpart = cent2 + 3136;                      // 6272
  float* kld   = kpart + 6272;                      // 2
  float* mmpart= kld + 2;                           // 2*1250
  float* gmm   = mmpart + 2500;                     // 2 (unused, kept for layout)
  float* zmean = gmm + 2;                           // 2*1856 = 3712
  float* psum  = zmean + 3712;                      // 2*29*49*64 = 181,888
  const int NBLK = 50 * 25;                         // 1250 dist blocks

  // 1. fused pool p2 + p3 (one launch)
  poolf_k<<<3136 + 1568, 256, 0, stream>>>(p2, pp2, p3, pp3);
  // 2. fused build + transpose (fp8 interleaved) + channel partial sums
  buildzt_k<<<dim3(49, 29, NBb), 256, 0, stream>>>(p1, pp2, pp3, zt8, psum);
  zred_k<<<dim3(29, NBb), 64, 0, stream>>>(psum, zmean);
  // 3. weight convert (bf16 for eca + interleaved fp8 for GEMM) + C transpose
  convW_k<<<(DIMc * KP + 255) / 256, 256, 0, stream>>>(wcoord, Wb, Wb8);
  transC_k<<<dim3(50, 29, 1), 256, 0, stream>>>(Cm, Ct, Ct8);
  // 4. eca gate from zmean matvec
  yv_k<<<dim3(DIMc / 16, NBb), 256, 0, stream>>>(Wb, zmean, bcoord, yv);
  fac_k<<<(NBb * DIMc + 255) / 256, 256, 0, stream>>>(yv, weca, fac);
  // 5. phi_t = (z_t @ Wb^T + bias) * fac; fp8 BK=64, K=29 tiles of 64 (covers coord chans)
  gemm8_k<0><<<50 * 14, 256, 0, stream>>>(
      zt8, Wb8, 14, 29, bcoord, fac, phi,
      nullptr, nullptr, nullptr, nullptr, nullptr, 0);
  // 6. fused row pass: cent2 + C softmax + feat2/kpart + interleaved phi8 (grid 3200)
  rowfuse_k<<<MP, 256, 0, stream>>>(Ct, phi, phi8, cent2, feat2, kpart);
  kldred_k<<<1, 256, 0, stream>>>(kpart, kld);
  // 7. dist = (feat2 + cent2 - 2 phi8 Ct8) * kld; fp8 BK=64, K=28 tiles (pad group zero, skipped)
  gemm8_k<1><<<50 * 25, 256, 0, stream>>>(
      phi8, Ct8, 25, 28, nullptr, nullptr, nullptr,
      feat2, cent2, kld, dist, mmpart, NBLK);
  // 8. soft top-k (wave-per-row fixed-point, mmpart reduce folded in) + weighted sum + sqrt
  topk_k<<<NBb * HWn / 4, 256, 0, stream>>>(dist, mmpart, NBLK, out);
}